// Round 6
// baseline (519.830 us; speedup 1.0000x reference)
//
#include <hip/hip_runtime.h>
#include <hip/hip_bf16.h>

#define Bn 256
#define Tn 200
#define En 100
#define Hn 128
#define Kn 13
#define G4 512          // 4H
#define BT 51200        // B*T

typedef __attribute__((ext_vector_type(8))) __bf16 bf8_t;
typedef __attribute__((ext_vector_type(4))) float f4_t;

__device__ __forceinline__ unsigned short f2bf(float f) {
  unsigned int u = __float_as_uint(f);
  u = (u + 0x7FFFu + ((u >> 16) & 1u)) >> 16;
  return (unsigned short)u;
}
__device__ __forceinline__ float bf2f(unsigned short s) {
  return __uint_as_float(((unsigned int)s) << 16);
}
__device__ __forceinline__ float sigm(float x) { return 1.f / (1.f + __expf(-x)); }

// ---------- lens ----------
__global__ __launch_bounds__(64) void k_lens(const int* __restrict__ text,
                                             int* __restrict__ lens_i,
                                             float* __restrict__ out_lens) {
  int b = blockIdx.x, lane = threadIdx.x;
  int cnt = 0;
  for (int t = lane; t < Tn; t += 64) cnt += (text[b * Tn + t] != 0);
  for (int off = 32; off; off >>= 1) cnt += __shfl_down(cnt, off);
  if (lane == 0) { lens_i[b] = cnt; out_lens[b] = (float)cnt; }
}

// ---------- W -> WT bf16 padded: wt[2][512][128] ----------
__global__ __launch_bounds__(256) void k_wt(const float* __restrict__ Wf,
                                            const float* __restrict__ Wb,
                                            unsigned short* __restrict__ wt) {
  int idx = blockIdx.x * 256 + threadIdx.x;   // 0..131071
  int dir = idx >> 16;
  int rem = idx & 65535;
  int n = rem >> 7, k = rem & 127;
  const float* W = dir ? Wb : Wf;
  float v = (k < En) ? W[k * G4 + n] : 0.f;
  wt[idx] = f2bf(v);
}

// ---------- embedding gather -> bf16 padded x[BT][128] ----------
__global__ __launch_bounds__(256) void k_gather(const int* __restrict__ text,
                                                const float* __restrict__ emb,
                                                unsigned short* __restrict__ xg) {
  int row = blockIdx.x * 128 + (threadIdx.x >> 1);
  int half = threadIdx.x & 1;
  int tok = text[row];
  const float* er = emb + (size_t)tok * En;
  unsigned short* xr = xg + (size_t)row * 128 + half * 64;
  #pragma unroll
  for (int c = 0; c < 64; c += 2) {
    int col = half * 64 + c;
    float v0 = (col < En) ? er[col] : 0.f;
    float v1 = (col + 1 < En) ? er[col + 1] : 0.f;
    unsigned int pk = (unsigned int)f2bf(v0) | ((unsigned int)f2bf(v1) << 16);
    *(unsigned int*)(xr + c) = pk;
  }
}

// ---------- xw = x@W + b  (MFMA bf16, single K-tile=128) ----------
__global__ __launch_bounds__(256) void k_gemm_xw(const unsigned short* __restrict__ xg,
                                                 const unsigned short* __restrict__ wt,
                                                 const float* __restrict__ biasf,
                                                 const float* __restrict__ biasb,
                                                 unsigned short* __restrict__ xwf,
                                                 unsigned short* __restrict__ xwb) {
  __shared__ unsigned short As[128 * 128];
  __shared__ unsigned short Bs[128 * 128];
  int mt = blockIdx.x;              // 0..399
  int dir = blockIdx.y >> 2;        // 0=f,1=b
  int nt = blockIdx.y & 3;          // 0..3 (128-wide N tiles)
  const float* bias = dir ? biasb : biasf;
  unsigned short* out = dir ? xwb : xwf;
  int tid = threadIdx.x;
  const unsigned short* wt_d = wt + (size_t)dir * (G4 * 128);

  #pragma unroll
  for (int it = 0; it < 8; it++) {
    int idx = it * 256 + tid;
    int r = idx >> 4, c = idx & 15;
    bf8_t va = *(const bf8_t*)(xg + ((size_t)mt * 128 + r) * 128 + c * 8);
    bf8_t vb = *(const bf8_t*)(wt_d + ((size_t)nt * 128 + r) * 128 + c * 8);
    int byte = (r * 256 + c * 16) ^ ((r & 7) << 4);
    *(bf8_t*)((char*)As + byte) = va;
    *(bf8_t*)((char*)Bs + byte) = vb;
  }
  __syncthreads();
  int wid = tid >> 6, lane = tid & 63;
  int wm = wid >> 1, wn = wid & 1;
  int lr = lane & 15, lk = lane >> 4;
  f4_t zero = {0.f, 0.f, 0.f, 0.f};
  f4_t acc[4][4];
  #pragma unroll
  for (int m = 0; m < 4; m++)
    #pragma unroll
    for (int n = 0; n < 4; n++) acc[m][n] = zero;
  #pragma unroll
  for (int kk = 0; kk < 4; kk++) {
    bf8_t af[4], bv[4];
    #pragma unroll
    for (int m = 0; m < 4; m++) {
      int r = wm * 64 + m * 16 + lr;
      int byte = (r * 256 + kk * 64 + lk * 16) ^ ((r & 7) << 4);
      af[m] = *(const bf8_t*)((const char*)As + byte);
    }
    #pragma unroll
    for (int n = 0; n < 4; n++) {
      int r = wn * 64 + n * 16 + lr;
      int byte = (r * 256 + kk * 64 + lk * 16) ^ ((r & 7) << 4);
      bv[n] = *(const bf8_t*)((const char*)Bs + byte);
    }
    #pragma unroll
    for (int m = 0; m < 4; m++)
      #pragma unroll
      for (int n = 0; n < 4; n++)
        acc[m][n] = __builtin_amdgcn_mfma_f32_16x16x32_bf16(af[m], bv[n], acc[m][n], 0, 0, 0);
  }
  #pragma unroll
  for (int m = 0; m < 4; m++) {
    int rowl = wm * 64 + m * 16 + lk * 4;
    #pragma unroll
    for (int n = 0; n < 4; n++) {
      int colg = nt * 128 + wn * 64 + n * 16 + lr;
      float bvs = bias[colg];
      #pragma unroll
      for (int q = 0; q < 4; q++) {
        size_t row = (size_t)mt * 128 + rowl + q;
        out[row * G4 + colg] = f2bf(acc[m][n][q] + bvs);
      }
    }
  }
}

// ---------- recurrent scan: 256 blocks (128 fwd + 128 bwd), 2 batch rows each ----------
// R3: float u[128] -> scratch (VGPR=92, 337us). R4: named SSA -> compiler SANK the
// loop-invariant U loads into the time loop chasing phantom occupancy (VGPR=84,
// 361us; grid=256 blocks on 256 CUs means only 1 block/CU can ever be resident,
// OccupancyPercent=23% == 8 waves == 2/SIMD already). Fix: pin waves/EU to
// exactly 2 via amdgpu_waves_per_eu(2,2) -> 256-VGPR budget, no sinking
// incentive; plus asm pins to make the loaded values non-rematerializable.
#define RPT32(M) M(0) M(1) M(2) M(3) M(4) M(5) M(6) M(7) M(8) M(9) M(10) M(11) \
  M(12) M(13) M(14) M(15) M(16) M(17) M(18) M(19) M(20) M(21) M(22) M(23) \
  M(24) M(25) M(26) M(27) M(28) M(29) M(30) M(31)

__global__ __attribute__((amdgpu_flat_work_group_size(512, 512),
                          amdgpu_waves_per_eu(2, 2)))
void k_scan(const float* __restrict__ Uf,
            const float* __restrict__ Ub,
            const unsigned short* __restrict__ xwf,
            const unsigned short* __restrict__ xwb,
            unsigned short* __restrict__ hf,
            unsigned short* __restrict__ hb) {
  int blk = blockIdx.x;
  int dir = blk >> 7;
  int pair = blk & 127;
  const float* U = dir ? Ub : Uf;
  const unsigned short* xw = dir ? xwb : xwf;
  unsigned short* hout = dir ? hb : hf;
  int b0 = pair * 2, b1 = b0 + 1;
  int j = threadIdx.x;

#define LOADU(i) f4_t uv##i; { const float* up = U + (size_t)(4 * (i)) * G4 + j; \
  uv##i[0] = up[0]; uv##i[1] = up[G4]; uv##i[2] = up[2 * G4]; uv##i[3] = up[3 * G4]; } \
  asm volatile("" : "+v"(uv##i));
  RPT32(LOADU)
#undef LOADU

  __shared__ __align__(16) float hbf[2][128];
  __shared__ float zbf[2][512];
  if (j < 128) { hbf[0][j] = 0.f; hbf[1][j] = 0.f; }
  float cst = 0.f;
  int ebs = (j >> 7) & 1, ejj = j & 127;
  const unsigned short* xp0 = xw + (size_t)b0 * Tn * G4 + j;
  const unsigned short* xp1 = xw + (size_t)b1 * Tn * G4 + j;
  unsigned short* hp = hout + (size_t)(ebs ? b1 : b0) * Tn * Hn + ejj;
  int t0 = dir ? (Tn - 1) : 0;
  int dt = dir ? -1 : 1;
  float xn0 = bf2f(xp0[(size_t)t0 * G4]);
  float xn1 = bf2f(xp1[(size_t)t0 * G4]);
  __syncthreads();
  int t = t0;
  for (int tt = 0; tt < Tn; tt++) {
    float z0 = xn0, z1 = xn1;
    int tnext = t + dt;
    if (tt < Tn - 1) {                // prefetch next step's xw
      xn0 = bf2f(xp0[(size_t)tnext * G4]);
      xn1 = bf2f(xp1[(size_t)tnext * G4]);
    }
#define FMAS(i) { const float4 h0 = *(const float4*)&hbf[0][4 * (i)]; \
                  const float4 h1 = *(const float4*)&hbf[1][4 * (i)]; \
  z0 = fmaf(h0.x, uv##i[0], z0); z0 = fmaf(h0.y, uv##i[1], z0); \
  z0 = fmaf(h0.z, uv##i[2], z0); z0 = fmaf(h0.w, uv##i[3], z0); \
  z1 = fmaf(h1.x, uv##i[0], z1); z1 = fmaf(h1.y, uv##i[1], z1); \
  z1 = fmaf(h1.z, uv##i[2], z1); z1 = fmaf(h1.w, uv##i[3], z1); }
    RPT32(FMAS)
#undef FMAS
    zbf[0][j] = z0;
    zbf[1][j] = z1;
    __syncthreads();
    if (j < 256) {
      float zi = zbf[ebs][ejj];
      float zf = zbf[ebs][ejj + 128];
      float zg = zbf[ebs][ejj + 256];
      float zo = zbf[ebs][ejj + 384];
      float ig = sigm(zi), fg = sigm(zf);
      float gg = fmaxf(zg, 0.f);
      cst = fmaf(fg, cst, ig * gg);
      float hv = sigm(zo) * fmaxf(cst, 0.f);
      hbf[ebs][ejj] = hv;
      hp[(size_t)t * Hn] = f2bf(hv);
    }
    __syncthreads();
    t = tnext;
  }
}

// ---------- logits = softmax([hf|hb] @ Wd + bd) ----------
__global__ __launch_bounds__(128) void k_logits(const unsigned short* __restrict__ hf,
                                                const unsigned short* __restrict__ hb,
                                                const float* __restrict__ Wd,
                                                const float* __restrict__ bd,
                                                float* __restrict__ out) {
  __shared__ unsigned short hs[128 * 256];   // 64KB, XOR-swizzled rows of 512B
  int tid = threadIdx.x;
  size_t row0 = (size_t)blockIdx.x * 128;
  #pragma unroll
  for (int it = 0; it < 16; it++) {
    int idx = it * 128 + tid;
    int r = idx >> 4, c = idx & 15;
    bf8_t vf = *(const bf8_t*)(hf + (row0 + r) * 128 + c * 8);
    bf8_t vb = *(const bf8_t*)(hb + (row0 + r) * 128 + c * 8);
    int byte = (r * 512 + c * 16) ^ ((r & 7) << 4);
    *(bf8_t*)((char*)hs + byte) = vf;
    int byte2 = (r * 512 + 256 + c * 16) ^ ((r & 7) << 4);
    *(bf8_t*)((char*)hs + byte2) = vb;
  }
  __syncthreads();
  float acc[Kn];
  #pragma unroll
  for (int jj = 0; jj < Kn; jj++) acc[jj] = bd[jj];
  int r = tid;
  #pragma unroll 4
  for (int c = 0; c < 32; c++) {
    int byte = (r * 512 + c * 16) ^ ((r & 7) << 4);
    bf8_t v = *(const bf8_t*)((const char*)hs + byte);
    #pragma unroll
    for (int e = 0; e < 8; e++) {
      float h = (float)v[e];
      int k = c * 8 + e;
      #pragma unroll
      for (int jj = 0; jj < Kn; jj++)
        acc[jj] = fmaf(h, Wd[k * Kn + jj], acc[jj]);   // uniform -> scalar loads
    }
  }
  float m = acc[0];
  #pragma unroll
  for (int jj = 1; jj < Kn; jj++) m = fmaxf(m, acc[jj]);
  float s = 0.f;
  #pragma unroll
  for (int jj = 0; jj < Kn; jj++) { acc[jj] = __expf(acc[jj] - m); s += acc[jj]; }
  float inv = 1.f / s;
  float* op = out + (row0 + r) * Kn;
  #pragma unroll
  for (int jj = 0; jj < Kn; jj++) op[jj] = acc[jj] * inv;
}

// ---------- CRF log-likelihood: one wave per batch row ----------
__global__ __launch_bounds__(64) void k_crf(const float* __restrict__ logits,
                                            const int* __restrict__ labels,
                                            const int* __restrict__ lens_i,
                                            const float* __restrict__ trans,
                                            float* __restrict__ out_ll) {
  int b = blockIdx.x, lane = threadIdx.x;
  int len = lens_i[b];
  const float* lg = logits + (size_t)b * Tn * Kn;
  const int* lab = labels + (size_t)b * Tn;
  // unary + pairwise scores (parallel over t)
  float sc = 0.f;
  for (int t = lane; t < Tn; t += 64) {
    if (t < len) {
      sc += lg[t * Kn + lab[t]];
      if (t >= 1) sc += trans[lab[t - 1] * Kn + lab[t]];
    }
  }
  for (int off = 32; off; off >>= 1) sc += __shfl_down(sc, off);
  // alpha recursion on lanes 0..12
  bool act = lane < Kn;
  int jl = act ? lane : 0;
  float etr[Kn];
  #pragma unroll
  for (int i = 0; i < Kn; i++) etr[i] = __expf(trans[i * Kn + jl]);
  float a = act ? lg[jl] : -INFINITY;
  float lgv = (len > 1) ? lg[Kn + jl] : 0.f;
  for (int t = 1; t < len; t++) {
    float lgn = (t + 1 < len) ? lg[(t + 1) * Kn + jl] : 0.f;   // prefetch
    float m = a;
    for (int off = 8; off; off >>= 1) m = fmaxf(m, __shfl_xor(m, off, 16));
    float ea = __expf(a - m);
    float s = 0.f;
    #pragma unroll
    for (int i = 0; i < Kn; i++) s = fmaf(__shfl(ea, i), etr[i], s);
    float anew = m + __logf(s) + lgv;
    if (act) a = anew;
    lgv = lgn;
  }
  float m2 = a;
  for (int off = 8; off; off >>= 1) m2 = fmaxf(m2, __shfl_xor(m2, off, 16));
  float ea2 = act ? __expf(a - m2) : 0.f;
  float ssum = ea2;
  for (int off = 8; off; off >>= 1) ssum += __shfl_xor(ssum, off, 16);
  float logZ = m2 + __logf(ssum);
  if (lane == 0) out_ll[b] = sc - logZ;
}

extern "C" void kernel_launch(void* const* d_in, const int* in_sizes, int n_in,
                              void* d_out, int out_size, void* d_ws, size_t ws_size,
                              hipStream_t stream) {
  const int* text = (const int*)d_in[0];
  const int* labels = (const int*)d_in[1];
  const float* emb = (const float*)d_in[2];
  const float* Wf = (const float*)d_in[3];
  const float* Uf = (const float*)d_in[4];
  const float* bf_ = (const float*)d_in[5];
  const float* Wb = (const float*)d_in[6];
  const float* Ub = (const float*)d_in[7];
  const float* bb_ = (const float*)d_in[8];
  const float* Wd = (const float*)d_in[9];
  const float* bd = (const float*)d_in[10];
  const float* trans = (const float*)d_in[11];
  (void)in_sizes; (void)n_in; (void)out_size; (void)ws_size;

  float* out = (float*)d_out;
  float* out_logits = out;                       // [BT*K]
  float* out_lens = out + (size_t)BT * Kn;       // [B]
  float* out_ll = out_lens + Bn;                 // [B]

  char* ws = (char*)d_ws;
  size_t o = 0;
  int* lens_i = (int*)(ws + o);                o += 1024;
  unsigned short* wt = (unsigned short*)(ws + o);  o += (size_t)2 * G4 * 128 * 2;
  unsigned short* xg = (unsigned short*)(ws + o);  o += (size_t)BT * 128 * 2;
  unsigned short* xwf = (unsigned short*)(ws + o); o += (size_t)BT * G4 * 2;
  unsigned short* xwb = (unsigned short*)(ws + o); o += (size_t)BT * G4 * 2;
  unsigned short* hfb = (unsigned short*)(ws + o); o += (size_t)BT * Hn * 2;
  unsigned short* hbb = (unsigned short*)(ws + o); o += (size_t)BT * Hn * 2;

  hipLaunchKernelGGL(k_lens, dim3(Bn), dim3(64), 0, stream, text, lens_i, out_lens);
  hipLaunchKernelGGL(k_wt, dim3(512), dim3(256), 0, stream, Wf, Wb, wt);
  hipLaunchKernelGGL(k_gather, dim3(400), dim3(256), 0, stream, text, emb, xg);
  hipLaunchKernelGGL(k_gemm_xw, dim3(400, 8), dim3(256), 0, stream, xg, wt, bf_, bb_, xwf, xwb);
  hipLaunchKernelGGL(k_scan, dim3(256), dim3(512), 0, stream, Uf, Ub, xwf, xwb, hfb, hbb);
  hipLaunchKernelGGL(k_logits, dim3(400), dim3(128), 0, stream, hfb, hbb, Wd, bd, out_logits);
  hipLaunchKernelGGL(k_crf, dim3(Bn), dim3(64), 0, stream, out_logits, labels, lens_i, trans, out_ll);
}

// Round 7
// 454.674 us; speedup vs baseline: 1.1433x; 1.1433x over previous
//
#include <hip/hip_runtime.h>
#include <hip/hip_bf16.h>

#define Bn 256
#define Tn 200
#define En 100
#define Hn 128
#define Kn 13
#define G4 512          // 4H
#define BT 51200        // B*T

typedef __attribute__((ext_vector_type(8))) __bf16 bf8_t;
typedef __attribute__((ext_vector_type(4))) float f4_t;

__device__ __forceinline__ unsigned short f2bf(float f) {
  unsigned int u = __float_as_uint(f);
  u = (u + 0x7FFFu + ((u >> 16) & 1u)) >> 16;
  return (unsigned short)u;
}
__device__ __forceinline__ float bf2f(unsigned short s) {
  return __uint_as_float(((unsigned int)s) << 16);
}
__device__ __forceinline__ float sigm(float x) { return 1.f / (1.f + __expf(-x)); }

// Gate permutation: column n of the permuted weight space holds original
// column m(n) = g*128 + j with g=(n>>4)&3, j=(n>>6)*16+(n&15). With the scan's
// wave-w/4-Ntile decomposition (n = w*64 + nt*16 + c) this puts gates i,f,g,o
// of logical unit j = w*16+c into acc tiles nt=0..3 of ONE lane.
__device__ __forceinline__ int gperm(int n) {
  return ((n >> 4) & 3) * 128 + ((n >> 6) << 4) + (n & 15);
}

// ---------- lens ----------
__global__ __launch_bounds__(64) void k_lens(const int* __restrict__ text,
                                             int* __restrict__ lens_i,
                                             float* __restrict__ out_lens) {
  int b = blockIdx.x, lane = threadIdx.x;
  int cnt = 0;
  for (int t = lane; t < Tn; t += 64) cnt += (text[b * Tn + t] != 0);
  for (int off = 32; off; off >>= 1) cnt += __shfl_down(cnt, off);
  if (lane == 0) { lens_i[b] = cnt; out_lens[b] = (float)cnt; }
}

// ---------- W,U -> permuted-transposed bf16: wt[2][512][128], ut[2][512][128] ----------
__global__ __launch_bounds__(256) void k_wt(const float* __restrict__ Wf,
                                            const float* __restrict__ Wb,
                                            const float* __restrict__ Uf,
                                            const float* __restrict__ Ub,
                                            unsigned short* __restrict__ wt,
                                            unsigned short* __restrict__ ut) {
  int idx = blockIdx.x * 256 + threadIdx.x;   // 0..262143
  int half = idx >> 17;                        // 0:W  1:U
  int rem = idx & 131071;
  int dir = rem >> 16;
  int nk = rem & 65535;
  int n = nk >> 7, k = nk & 127;
  int mc = gperm(n);
  if (half == 0) {
    const float* W = dir ? Wb : Wf;
    wt[rem] = f2bf((k < En) ? W[k * G4 + mc] : 0.f);
  } else {
    const float* U = dir ? Ub : Uf;
    ut[rem] = f2bf(U[k * G4 + mc]);
  }
}

// ---------- embedding gather -> bf16 padded x[BT][128] ----------
__global__ __launch_bounds__(256) void k_gather(const int* __restrict__ text,
                                                const float* __restrict__ emb,
                                                unsigned short* __restrict__ xg) {
  int row = blockIdx.x * 128 + (threadIdx.x >> 1);
  int half = threadIdx.x & 1;
  int tok = text[row];
  const float* er = emb + (size_t)tok * En;
  unsigned short* xr = xg + (size_t)row * 128 + half * 64;
  #pragma unroll
  for (int c = 0; c < 64; c += 2) {
    int col = half * 64 + c;
    float v0 = (col < En) ? er[col] : 0.f;
    float v1 = (col + 1 < En) ? er[col + 1] : 0.f;
    unsigned int pk = (unsigned int)f2bf(v0) | ((unsigned int)f2bf(v1) << 16);
    *(unsigned int*)(xr + c) = pk;
  }
}

// ---------- xw = x@Wperm + bperm, stored [dir][t][b][512] for the scan ----------
__global__ __launch_bounds__(256) void k_gemm_xw(const unsigned short* __restrict__ xg,
                                                 const unsigned short* __restrict__ wt,
                                                 const float* __restrict__ biasf,
                                                 const float* __restrict__ biasb,
                                                 unsigned short* __restrict__ xwf,
                                                 unsigned short* __restrict__ xwb) {
  __shared__ unsigned short As[128 * 128];
  __shared__ unsigned short Bs[128 * 128];
  int mt = blockIdx.x;              // 0..399
  int dir = blockIdx.y >> 2;        // 0=f,1=b
  int nt = blockIdx.y & 3;          // 0..3 (128-wide N tiles)
  const float* bias = dir ? biasb : biasf;
  unsigned short* out = dir ? xwb : xwf;
  int tid = threadIdx.x;
  const unsigned short* wt_d = wt + (size_t)dir * (G4 * 128);

  #pragma unroll
  for (int it = 0; it < 8; it++) {
    int idx = it * 256 + tid;
    int r = idx >> 4, c = idx & 15;
    bf8_t va = *(const bf8_t*)(xg + ((size_t)mt * 128 + r) * 128 + c * 8);
    bf8_t vb = *(const bf8_t*)(wt_d + ((size_t)nt * 128 + r) * 128 + c * 8);
    int byte = (r * 256 + c * 16) ^ ((r & 7) << 4);
    *(bf8_t*)((char*)As + byte) = va;
    *(bf8_t*)((char*)Bs + byte) = vb;
  }
  __syncthreads();
  int wid = tid >> 6, lane = tid & 63;
  int wm = wid >> 1, wn = wid & 1;
  int lr = lane & 15, lk = lane >> 4;
  f4_t zero = {0.f, 0.f, 0.f, 0.f};
  f4_t acc[4][4];
  #pragma unroll
  for (int m = 0; m < 4; m++)
    #pragma unroll
    for (int n = 0; n < 4; n++) acc[m][n] = zero;
  #pragma unroll
  for (int kk = 0; kk < 4; kk++) {
    bf8_t af[4], bv[4];
    #pragma unroll
    for (int m = 0; m < 4; m++) {
      int r = wm * 64 + m * 16 + lr;
      int byte = (r * 256 + kk * 64 + lk * 16) ^ ((r & 7) << 4);
      af[m] = *(const bf8_t*)((const char*)As + byte);
    }
    #pragma unroll
    for (int n = 0; n < 4; n++) {
      int r = wn * 64 + n * 16 + lr;
      int byte = (r * 256 + kk * 64 + lk * 16) ^ ((r & 7) << 4);
      bv[n] = *(const bf8_t*)((const char*)Bs + byte);
    }
    #pragma unroll
    for (int m = 0; m < 4; m++)
      #pragma unroll
      for (int n = 0; n < 4; n++)
        acc[m][n] = __builtin_amdgcn_mfma_f32_16x16x32_bf16(af[m], bv[n], acc[m][n], 0, 0, 0);
  }
  #pragma unroll
  for (int m = 0; m < 4; m++) {
    int rowl = wm * 64 + m * 16 + lk * 4;
    #pragma unroll
    for (int q = 0; q < 4; q++) {
      int row = mt * 128 + rowl + q;
      int b = row / 200;
      int t = row - b * 200;
      size_t base = ((size_t)t * Bn + b) * G4;
      #pragma unroll
      for (int n = 0; n < 4; n++) {
        int colg = nt * 128 + wn * 64 + n * 16 + lr;
        out[base + colg] = f2bf(acc[m][n][q] + bias[gperm(colg)]);
      }
    }
  }
}

// ---------- recurrent scan, MFMA version ----------
// R3/R4/R6 lesson: the RA refuses to keep 128 fp32 loop-invariants resident in
// a VALU loop (scratch 337us / sink 361us / spill-despite-pins 374us). This
// version: 32 blocks x 512 thr, 16 batch rows/block; z = h@U via 16 MFMAs/wave
// (U B-frags = 16 named bf8_t = 64 VGPR, asm-pinned). Gate-permuted columns put
// i,f,g,o of unit j in one lane's acc0..3 -> gates fully in-thread, c-state in
// 4 named floats, no z roundtrip. h double-buffered in 8KB swizzled LDS,
// ONE barrier/step. xw ([dir][t][b][512]) prefetched one step ahead.
#define UB16(M) M(0,0) M(0,1) M(0,2) M(0,3) M(1,0) M(1,1) M(1,2) M(1,3) \
                M(2,0) M(2,1) M(2,2) M(2,3) M(3,0) M(3,1) M(3,2) M(3,3)
#define XN16(M) M(0,0) M(0,1) M(0,2) M(0,3) M(1,0) M(1,1) M(1,2) M(1,3) \
                M(2,0) M(2,1) M(2,2) M(2,3) M(3,0) M(3,1) M(3,2) M(3,3)

__global__ __attribute__((amdgpu_flat_work_group_size(512, 512),
                          amdgpu_waves_per_eu(2, 2)))
void k_scan(const unsigned short* __restrict__ ut,
            const unsigned short* __restrict__ xw_s,
            unsigned short* __restrict__ hf,
            unsigned short* __restrict__ hb) {
  int blk = blockIdx.x;              // 0..31
  int dir = blk >> 4;
  int b0 = (blk & 15) * 16;
  int tid = threadIdx.x;
  int w = tid >> 6, l = tid & 63;
  int lr = l & 15, lg = l >> 4;
  int lg16 = lg * 16;
  int lswz = (lr & 7) << 4;
  int r0 = lg * 4;
  int jj = w * 16 + lr;
  int jj2 = jj * 2;
  const unsigned short* ut_d = ut + (size_t)dir * (G4 * 128);
  const unsigned short* xw_d = xw_s + (size_t)dir * ((size_t)Tn * Bn * G4);
  unsigned short* hout = dir ? hb : hf;

  // U B-frags, resident: frag(nt,kk) covers cols w*64+nt*16+(l&15), k=kk*32+(l>>4)*8..+7
#define LOADUB(nt, kk) \
  bf8_t ub_##nt##_##kk = *(const bf8_t*)(ut_d + (size_t)(w * 64 + (nt) * 16 + lr) * 128 + (kk) * 32 + lg * 8); \
  asm volatile("" : "+v"(ub_##nt##_##kk));
  UB16(LOADUB)
#undef LOADUB

  __shared__ unsigned short h_lds[2][2048];   // [16 rows][128] bf16, XOR-swizzled
  for (int i = tid; i < 2048; i += 512) h_lds[0][i] = 0;
  unsigned short* hcur = &h_lds[0][0];
  unsigned short* hnxt = &h_lds[1][0];
  float c0 = 0.f, c1 = 0.f, c2 = 0.f, c3 = 0.f;

  int t = dir ? (Tn - 1) : 0;
  int dt = dir ? -1 : 1;
  int tn = t;
#define DECLXN(nt, q) unsigned short xn_##nt##_##q;
  XN16(DECLXN)
#undef DECLXN
#define PXN(nt, q) xn_##nt##_##q = xw_d[((size_t)tn * Bn + b0 + r0 + (q)) * G4 + (w * 64 + (nt) * 16 + lr)];
  XN16(PXN)
  __syncthreads();

  for (int tt = 0; tt < Tn; tt++) {
    // acc init = xw (C-in), consuming the prefetch
    f4_t acc0, acc1, acc2, acc3;
#define AINIT(nt) \
    acc##nt[0] = bf2f(xn_##nt##_0); acc##nt[1] = bf2f(xn_##nt##_1); \
    acc##nt[2] = bf2f(xn_##nt##_2); acc##nt[3] = bf2f(xn_##nt##_3);
    AINIT(0) AINIT(1) AINIT(2) AINIT(3)
#undef AINIT
    if (tt < Tn - 1) {               // prefetch next step's xw
      tn = t + dt;
      XN16(PXN)
    }
    // A-frags from h_lds (prev h), swizzled
#define AF(kk) bf8_t af##kk = *(const bf8_t*)((const char*)hcur + ((lr * 256 + (kk) * 64 + lg16) ^ lswz));
    AF(0) AF(1) AF(2) AF(3)
#undef AF
#define MF(nt, kk) acc##nt = __builtin_amdgcn_mfma_f32_16x16x32_bf16(af##kk, ub_##nt##_##kk, acc##nt, 0, 0, 0);
    MF(0,0) MF(1,0) MF(2,0) MF(3,0)
    MF(0,1) MF(1,1) MF(2,1) MF(3,1)
    MF(0,2) MF(1,2) MF(2,2) MF(3,2)
    MF(0,3) MF(1,3) MF(2,3) MF(3,3)
#undef MF
    // gates: acc0..3 = i,f,g,o for unit jj, rows r0+q
#define GATE(q) { \
    float ig = sigm(acc0[q]); \
    float fg = sigm(acc1[q]); \
    float gg = fmaxf(acc2[q], 0.f); \
    c##q = fmaf(fg, c##q, ig * gg); \
    float hv = sigm(acc3[q]) * fmaxf(c##q, 0.f); \
    unsigned short hs2 = f2bf(hv); \
    int rr = r0 + (q); \
    *(unsigned short*)((char*)hnxt + ((rr * 256 + jj2) ^ ((rr & 7) << 4))) = hs2; \
    hout[((size_t)(b0 + rr) * Tn + t) * 128 + jj] = hs2; }
    GATE(0) GATE(1) GATE(2) GATE(3)
#undef GATE
    __syncthreads();
    unsigned short* tmp = hcur; hcur = hnxt; hnxt = tmp;
    t += dt;
  }
}

// ---------- logits = softmax([hf|hb] @ Wd + bd) ----------
__global__ __launch_bounds__(128) void k_logits(const unsigned short* __restrict__ hf,
                                                const unsigned short* __restrict__ hb,
                                                const float* __restrict__ Wd,
                                                const float* __restrict__ bd,
                                                float* __restrict__ out) {
  __shared__ unsigned short hs[128 * 256];   // 64KB, XOR-swizzled rows of 512B
  int tid = threadIdx.x;
  size_t row0 = (size_t)blockIdx.x * 128;
  #pragma unroll
  for (int it = 0; it < 16; it++) {
    int idx = it * 128 + tid;
    int r = idx >> 4, c = idx & 15;
    bf8_t vf = *(const bf8_t*)(hf + (row0 + r) * 128 + c * 8);
    bf8_t vb = *(const bf8_t*)(hb + (row0 + r) * 128 + c * 8);
    int byte = (r * 512 + c * 16) ^ ((r & 7) << 4);
    *(bf8_t*)((char*)hs + byte) = vf;
    int byte2 = (r * 512 + 256 + c * 16) ^ ((r & 7) << 4);
    *(bf8_t*)((char*)hs + byte2) = vb;
  }
  __syncthreads();
  float acc[Kn];
  #pragma unroll
  for (int jj = 0; jj < Kn; jj++) acc[jj] = bd[jj];
  int r = tid;
  #pragma unroll 4
  for (int c = 0; c < 32; c++) {
    int byte = (r * 512 + c * 16) ^ ((r & 7) << 4);
    bf8_t v = *(const bf8_t*)((const char*)hs + byte);
    #pragma unroll
    for (int e = 0; e < 8; e++) {
      float h = (float)v[e];
      int k = c * 8 + e;
      #pragma unroll
      for (int jj = 0; jj < Kn; jj++)
        acc[jj] = fmaf(h, Wd[k * Kn + jj], acc[jj]);   // uniform -> scalar loads
    }
  }
  float m = acc[0];
  #pragma unroll
  for (int jj = 1; jj < Kn; jj++) m = fmaxf(m, acc[jj]);
  float s = 0.f;
  #pragma unroll
  for (int jj = 0; jj < Kn; jj++) { acc[jj] = __expf(acc[jj] - m); s += acc[jj]; }
  float inv = 1.f / s;
  float* op = out + (row0 + r) * Kn;
  #pragma unroll
  for (int jj = 0; jj < Kn; jj++) op[jj] = acc[jj] * inv;
}

// ---------- CRF log-likelihood: one wave per batch row ----------
__global__ __launch_bounds__(64) void k_crf(const float* __restrict__ logits,
                                            const int* __restrict__ labels,
                                            const int* __restrict__ lens_i,
                                            const float* __restrict__ trans,
                                            float* __restrict__ out_ll) {
  int b = blockIdx.x, lane = threadIdx.x;
  int len = lens_i[b];
  const float* lg = logits + (size_t)b * Tn * Kn;
  const int* lab = labels + (size_t)b * Tn;
  float sc = 0.f;
  for (int t = lane; t < Tn; t += 64) {
    if (t < len) {
      sc += lg[t * Kn + lab[t]];
      if (t >= 1) sc += trans[lab[t - 1] * Kn + lab[t]];
    }
  }
  for (int off = 32; off; off >>= 1) sc += __shfl_down(sc, off);
  bool act = lane < Kn;
  int jl = act ? lane : 0;
  float etr[Kn];
  #pragma unroll
  for (int i = 0; i < Kn; i++) etr[i] = __expf(trans[i * Kn + jl]);
  float a = act ? lg[jl] : -INFINITY;
  float lgv = (len > 1) ? lg[Kn + jl] : 0.f;
  for (int t = 1; t < len; t++) {
    float lgn = (t + 1 < len) ? lg[(t + 1) * Kn + jl] : 0.f;
    float m = a;
    for (int off = 8; off; off >>= 1) m = fmaxf(m, __shfl_xor(m, off, 16));
    float ea = __expf(a - m);
    float s = 0.f;
    #pragma unroll
    for (int i = 0; i < Kn; i++) s = fmaf(__shfl(ea, i), etr[i], s);
    float anew = m + __logf(s) + lgv;
    if (act) a = anew;
    lgv = lgn;
  }
  float m2 = a;
  for (int off = 8; off; off >>= 1) m2 = fmaxf(m2, __shfl_xor(m2, off, 16));
  float ea2 = act ? __expf(a - m2) : 0.f;
  float ssum = ea2;
  for (int off = 8; off; off >>= 1) ssum += __shfl_xor(ssum, off, 16);
  float logZ = m2 + __logf(ssum);
  if (lane == 0) out_ll[b] = sc - logZ;
}

extern "C" void kernel_launch(void* const* d_in, const int* in_sizes, int n_in,
                              void* d_out, int out_size, void* d_ws, size_t ws_size,
                              hipStream_t stream) {
  const int* text = (const int*)d_in[0];
  const int* labels = (const int*)d_in[1];
  const float* emb = (const float*)d_in[2];
  const float* Wf = (const float*)d_in[3];
  const float* Uf = (const float*)d_in[4];
  const float* bf_ = (const float*)d_in[5];
  const float* Wb = (const float*)d_in[6];
  const float* Ub = (const float*)d_in[7];
  const float* bb_ = (const float*)d_in[8];
  const float* Wd = (const float*)d_in[9];
  const float* bd = (const float*)d_in[10];
  const float* trans = (const float*)d_in[11];
  (void)in_sizes; (void)n_in; (void)out_size; (void)ws_size;

  float* out = (float*)d_out;
  float* out_logits = out;                       // [BT*K]
  float* out_lens = out + (size_t)BT * Kn;       // [B]
  float* out_ll = out_lens + Bn;                 // [B]

  char* ws = (char*)d_ws;
  size_t o = 0;
  int* lens_i = (int*)(ws + o);                o += 1024;
  unsigned short* wt = (unsigned short*)(ws + o);  o += (size_t)2 * G4 * 128 * 2;
  unsigned short* ut = (unsigned short*)(ws + o);  o += (size_t)2 * G4 * 128 * 2;
  unsigned short* xg = (unsigned short*)(ws + o);  o += (size_t)BT * 128 * 2;
  unsigned short* xw_s = (unsigned short*)(ws + o); o += (size_t)2 * BT * G4 * 2;  // [dir][t][b][512]
  unsigned short* hfb = (unsigned short*)(ws + o); o += (size_t)BT * Hn * 2;
  unsigned short* hbb = (unsigned short*)(ws + o); o += (size_t)BT * Hn * 2;
  unsigned short* xwf = xw_s;
  unsigned short* xwb = xw_s + (size_t)BT * G4;

  hipLaunchKernelGGL(k_lens, dim3(Bn), dim3(64), 0, stream, text, lens_i, out_lens);
  hipLaunchKernelGGL(k_wt, dim3(1024), dim3(256), 0, stream, Wf, Wb, Uf, Ub, wt, ut);
  hipLaunchKernelGGL(k_gather, dim3(400), dim3(256), 0, stream, text, emb, xg);
  hipLaunchKernelGGL(k_gemm_xw, dim3(400, 8), dim3(256), 0, stream, xg, wt, bf_, bb_, xwf, xwb);
  hipLaunchKernelGGL(k_scan, dim3(32), dim3(512), 0, stream, ut, xw_s, hfb, hbb);
  hipLaunchKernelGGL(k_logits, dim3(400), dim3(128), 0, stream, hfb, hbb, Wd, bd, out_logits);
  hipLaunchKernelGGL(k_crf, dim3(Bn), dim3(64), 0, stream, out_logits, labels, lens_i, trans, out_ll);
}

// Round 8
// 444.732 us; speedup vs baseline: 1.1689x; 1.0224x over previous
//
#include <hip/hip_runtime.h>
#include <hip/hip_bf16.h>

#define Bn 256
#define Tn 200
#define En 100
#define Hn 128
#define Kn 13
#define G4 512          // 4H
#define BT 51200        // B*T

typedef __attribute__((ext_vector_type(8))) __bf16 bf8_t;
typedef __attribute__((ext_vector_type(4))) float f4_t;

__device__ __forceinline__ unsigned short f2bf(float f) {
  unsigned int u = __float_as_uint(f);
  u = (u + 0x7FFFu + ((u >> 16) & 1u)) >> 16;
  return (unsigned short)u;
}
__device__ __forceinline__ float bf2f(unsigned short s) {
  return __uint_as_float(((unsigned int)s) << 16);
}
__device__ __forceinline__ float sigm(float x) { return 1.f / (1.f + __expf(-x)); }

// Gate permutation: column n of the permuted weight space holds original
// column m(n) = g*128 + j with g=(n>>4)&3, j=(n>>6)*16+(n&15). With the scan's
// wave-w/4-Ntile decomposition (n = w*64 + nt*16 + c) this puts gates i,f,g,o
// of logical unit j = w*16+c into acc tiles nt=0..3 of ONE lane.
__device__ __forceinline__ int gperm(int n) {
  return ((n >> 4) & 3) * 128 + ((n >> 6) << 4) + (n & 15);
}

// ---------- lens ----------
__global__ __launch_bounds__(64) void k_lens(const int* __restrict__ text,
                                             int* __restrict__ lens_i,
                                             float* __restrict__ out_lens) {
  int b = blockIdx.x, lane = threadIdx.x;
  int cnt = 0;
  for (int t = lane; t < Tn; t += 64) cnt += (text[b * Tn + t] != 0);
  for (int off = 32; off; off >>= 1) cnt += __shfl_down(cnt, off);
  if (lane == 0) { lens_i[b] = cnt; out_lens[b] = (float)cnt; }
}

// ---------- W,U -> permuted-transposed bf16: wt[2][512][128], ut[2][512][128] ----------
__global__ __launch_bounds__(256) void k_wt(const float* __restrict__ Wf,
                                            const float* __restrict__ Wb,
                                            const float* __restrict__ Uf,
                                            const float* __restrict__ Ub,
                                            unsigned short* __restrict__ wt,
                                            unsigned short* __restrict__ ut) {
  int idx = blockIdx.x * 256 + threadIdx.x;   // 0..262143
  int half = idx >> 17;                        // 0:W  1:U
  int rem = idx & 131071;
  int dir = rem >> 16;
  int nk = rem & 65535;
  int n = nk >> 7, k = nk & 127;
  int mc = gperm(n);
  if (half == 0) {
    const float* W = dir ? Wb : Wf;
    wt[rem] = f2bf((k < En) ? W[k * G4 + mc] : 0.f);
  } else {
    const float* U = dir ? Ub : Uf;
    ut[rem] = f2bf(U[k * G4 + mc]);
  }
}

// ---------- embedding gather -> bf16 padded x[BT][128] ----------
__global__ __launch_bounds__(256) void k_gather(const int* __restrict__ text,
                                                const float* __restrict__ emb,
                                                unsigned short* __restrict__ xg) {
  int row = blockIdx.x * 128 + (threadIdx.x >> 1);
  int half = threadIdx.x & 1;
  int tok = text[row];
  const float* er = emb + (size_t)tok * En;
  unsigned short* xr = xg + (size_t)row * 128 + half * 64;
  #pragma unroll
  for (int c = 0; c < 64; c += 2) {
    int col = half * 64 + c;
    float v0 = (col < En) ? er[col] : 0.f;
    float v1 = (col + 1 < En) ? er[col + 1] : 0.f;
    unsigned int pk = (unsigned int)f2bf(v0) | ((unsigned int)f2bf(v1) << 16);
    *(unsigned int*)(xr + c) = pk;
  }
}

// ---------- xw = x@Wperm + bperm, stored [dir][t][b][512] for the scan ----------
__global__ __launch_bounds__(256) void k_gemm_xw(const unsigned short* __restrict__ xg,
                                                 const unsigned short* __restrict__ wt,
                                                 const float* __restrict__ biasf,
                                                 const float* __restrict__ biasb,
                                                 unsigned short* __restrict__ xwf,
                                                 unsigned short* __restrict__ xwb) {
  __shared__ unsigned short As[128 * 128];
  __shared__ unsigned short Bs[128 * 128];
  int mt = blockIdx.x;              // 0..399
  int dir = blockIdx.y >> 2;        // 0=f,1=b
  int nt = blockIdx.y & 3;          // 0..3 (128-wide N tiles)
  const float* bias = dir ? biasb : biasf;
  unsigned short* out = dir ? xwb : xwf;
  int tid = threadIdx.x;
  const unsigned short* wt_d = wt + (size_t)dir * (G4 * 128);

  #pragma unroll
  for (int it = 0; it < 8; it++) {
    int idx = it * 256 + tid;
    int r = idx >> 4, c = idx & 15;
    bf8_t va = *(const bf8_t*)(xg + ((size_t)mt * 128 + r) * 128 + c * 8);
    bf8_t vb = *(const bf8_t*)(wt_d + ((size_t)nt * 128 + r) * 128 + c * 8);
    int byte = (r * 256 + c * 16) ^ ((r & 7) << 4);
    *(bf8_t*)((char*)As + byte) = va;
    *(bf8_t*)((char*)Bs + byte) = vb;
  }
  __syncthreads();
  int wid = tid >> 6, lane = tid & 63;
  int wm = wid >> 1, wn = wid & 1;
  int lr = lane & 15, lk = lane >> 4;
  f4_t zero = {0.f, 0.f, 0.f, 0.f};
  f4_t acc[4][4];
  #pragma unroll
  for (int m = 0; m < 4; m++)
    #pragma unroll
    for (int n = 0; n < 4; n++) acc[m][n] = zero;
  #pragma unroll
  for (int kk = 0; kk < 4; kk++) {
    bf8_t af[4], bv[4];
    #pragma unroll
    for (int m = 0; m < 4; m++) {
      int r = wm * 64 + m * 16 + lr;
      int byte = (r * 256 + kk * 64 + lk * 16) ^ ((r & 7) << 4);
      af[m] = *(const bf8_t*)((const char*)As + byte);
    }
    #pragma unroll
    for (int n = 0; n < 4; n++) {
      int r = wn * 64 + n * 16 + lr;
      int byte = (r * 256 + kk * 64 + lk * 16) ^ ((r & 7) << 4);
      bv[n] = *(const bf8_t*)((const char*)Bs + byte);
    }
    #pragma unroll
    for (int m = 0; m < 4; m++)
      #pragma unroll
      for (int n = 0; n < 4; n++)
        acc[m][n] = __builtin_amdgcn_mfma_f32_16x16x32_bf16(af[m], bv[n], acc[m][n], 0, 0, 0);
  }
  float bn[4];
  #pragma unroll
  for (int n = 0; n < 4; n++) {
    int colg = nt * 128 + wn * 64 + n * 16 + lr;
    bn[n] = bias[gperm(colg)];
  }
  #pragma unroll
  for (int m = 0; m < 4; m++) {
    int rowl = wm * 64 + m * 16 + lk * 4;
    #pragma unroll
    for (int q = 0; q < 4; q++) {
      int row = mt * 128 + rowl + q;
      int b = row / 200;
      int t = row - b * 200;
      size_t base = ((size_t)t * Bn + b) * G4;
      #pragma unroll
      for (int n = 0; n < 4; n++) {
        int colg = nt * 128 + wn * 64 + n * 16 + lr;
        out[base + colg] = f2bf(acc[m][n][q] + bn[n]);
      }
    }
  }
}

// ---------- recurrent scan, MFMA version (R8) ----------
// R7 post-mortem: RA targeted 6 waves/EU (VGPR=88) and evicted the 64 U-frag
// VGPRs; per-step addressing re-done with 64-bit muls -> VALU-bound, 3250
// cyc/step. R8: (1) waves_per_eu(1,2) -> 512-reg budget, no spill pressure;
// (2) U-frags pinned into AGPRs ("+a") -- gfx950 MFMA reads B from AGPR
// natively; (3) zero-VALU addressing: xw/h via ONE incremented pointer +
// compile-time immediate offsets; LDS addrs precomputed, dbuf toggle = XOR.
#define UB16(M) M(0,0) M(0,1) M(0,2) M(0,3) M(1,0) M(1,1) M(1,2) M(1,3) \
                M(2,0) M(2,1) M(2,2) M(2,3) M(3,0) M(3,1) M(3,2) M(3,3)
#define XN16(M) M(0,0) M(0,1) M(0,2) M(0,3) M(1,0) M(1,1) M(1,2) M(1,3) \
                M(2,0) M(2,1) M(2,2) M(2,3) M(3,0) M(3,1) M(3,2) M(3,3)

__global__ __attribute__((amdgpu_flat_work_group_size(512, 512),
                          amdgpu_waves_per_eu(1, 2)))
void k_scan(const unsigned short* __restrict__ ut,
            const unsigned short* __restrict__ xw_s,
            unsigned short* __restrict__ hf,
            unsigned short* __restrict__ hb) {
  int blk = blockIdx.x;              // 0..31
  int dir = blk >> 4;
  int b0 = (blk & 15) * 16;
  int tid = threadIdx.x;
  int w = tid >> 6, l = tid & 63;
  int lr = l & 15, lg = l >> 4;
  int r0 = lg * 4;
  int jj = w * 16 + lr;
  const unsigned short* ut_d = ut + (size_t)dir * (G4 * 128);
  const unsigned short* xw_d = xw_s + (size_t)dir * ((size_t)Tn * Bn * G4);
  unsigned short* hout = dir ? hb : hf;
  int t0 = dir ? (Tn - 1) : 0;
  int dt = dir ? -1 : 1;

  // U B-frags, pinned into AGPRs: frag(nt,kk) = cols w*64+nt*16+lr, k=kk*32+lg*8..+7
#define LOADUB(nt, kk) \
  bf8_t ub_##nt##_##kk = *(const bf8_t*)(ut_d + (size_t)(w * 64 + (nt) * 16 + lr) * 128 + (kk) * 32 + lg * 8); \
  asm volatile("" : "+a"(ub_##nt##_##kk));
  UB16(LOADUB)
#undef LOADUB

  __shared__ unsigned short h_lds[2][2048];   // two 4KB halves, XOR-swizzled rows
  for (int i = tid; i < 1024; i += 512) ((unsigned int*)h_lds)[i] = 0;

  // precomputed LDS byte addresses; read buf0 / write buf1 first, toggle ^4096
  int rb0 = (lr * 256 +   0 + lg * 16) ^ ((lr & 7) << 4);
  int rb1 = (lr * 256 +  64 + lg * 16) ^ ((lr & 7) << 4);
  int rb2 = (lr * 256 + 128 + lg * 16) ^ ((lr & 7) << 4);
  int rb3 = (lr * 256 + 192 + lg * 16) ^ ((lr & 7) << 4);
  int wb0 = (((r0 + 0) * 256 + jj * 2) ^ (((r0 + 0) & 7) << 4)) + 4096;
  int wb1 = (((r0 + 1) * 256 + jj * 2) ^ (((r0 + 1) & 7) << 4)) + 4096;
  int wb2 = (((r0 + 2) * 256 + jj * 2) ^ (((r0 + 2) & 7) << 4)) + 4096;
  int wb3 = (((r0 + 3) * 256 + jj * 2) ^ (((r0 + 3) & 7) << 4)) + 4096;
  char* lbase = (char*)h_lds;

  // steady-state pointers: one add per step, imm offsets cover (nt,q)
  const unsigned short* xptr = xw_d + ((size_t)t0 * Bn + b0 + r0) * G4 + w * 64 + lr;
  unsigned short* hp = hout + ((size_t)t0 * Bn + b0 + r0) * 128 + jj;
  const long long xstep = (long long)dt * Bn * G4;
  const long long hstep = (long long)dt * Bn * 128;

#define DECLXN(nt, q) unsigned short xn_##nt##_##q;
  XN16(DECLXN)
#undef DECLXN
#define PXN(nt, q) xn_##nt##_##q = xptr[(q) * G4 + (nt) * 16];
  XN16(PXN)
  float c0 = 0.f, c1 = 0.f, c2 = 0.f, c3 = 0.f;
  __syncthreads();

  for (int tt = 0; tt < Tn; tt++) {
    f4_t acc0, acc1, acc2, acc3;
#define AINIT(nt) \
    acc##nt[0] = bf2f(xn_##nt##_0); acc##nt[1] = bf2f(xn_##nt##_1); \
    acc##nt[2] = bf2f(xn_##nt##_2); acc##nt[3] = bf2f(xn_##nt##_3);
    AINIT(0) AINIT(1) AINIT(2) AINIT(3)
#undef AINIT
    if (tt < Tn - 1) {               // prefetch next step's xw
      xptr += xstep;
      XN16(PXN)
    }
    bf8_t af0 = *(const bf8_t*)(lbase + rb0);
    bf8_t af1 = *(const bf8_t*)(lbase + rb1);
    bf8_t af2 = *(const bf8_t*)(lbase + rb2);
    bf8_t af3 = *(const bf8_t*)(lbase + rb3);
#define MF(nt, kk) acc##nt = __builtin_amdgcn_mfma_f32_16x16x32_bf16(af##kk, ub_##nt##_##kk, acc##nt, 0, 0, 0);
    MF(0,0) MF(1,0) MF(2,0) MF(3,0)
    MF(0,1) MF(1,1) MF(2,1) MF(3,1)
    MF(0,2) MF(1,2) MF(2,2) MF(3,2)
    MF(0,3) MF(1,3) MF(2,3) MF(3,3)
#undef MF
#define GATE(q) { \
    float ig = sigm(acc0[q]); \
    float fg = sigm(acc1[q]); \
    float gg = fmaxf(acc2[q], 0.f); \
    c##q = fmaf(fg, c##q, ig * gg); \
    float hv = sigm(acc3[q]) * fmaxf(c##q, 0.f); \
    unsigned short hs2 = f2bf(hv); \
    *(unsigned short*)(lbase + wb##q) = hs2; \
    hp[(q) * 128] = hs2; }
    GATE(0) GATE(1) GATE(2) GATE(3)
#undef GATE
    __syncthreads();
    rb0 ^= 4096; rb1 ^= 4096; rb2 ^= 4096; rb3 ^= 4096;
    wb0 ^= 4096; wb1 ^= 4096; wb2 ^= 4096; wb3 ^= 4096;
    hp += hstep;
  }
}

// ---------- logits = softmax([hf|hb] @ Wd + bd); h rows are (t*Bn+b) ----------
__global__ __launch_bounds__(128) void k_logits(const unsigned short* __restrict__ hf,
                                                const unsigned short* __restrict__ hb,
                                                const float* __restrict__ Wd,
                                                const float* __restrict__ bd,
                                                float* __restrict__ out) {
  __shared__ unsigned short hs[128 * 256];   // 64KB, XOR-swizzled rows of 512B
  int tid = threadIdx.x;
  size_t row0 = (size_t)blockIdx.x * 128;
  #pragma unroll
  for (int it = 0; it < 16; it++) {
    int idx = it * 128 + tid;
    int r = idx >> 4, c = idx & 15;
    bf8_t vf = *(const bf8_t*)(hf + (row0 + r) * 128 + c * 8);
    bf8_t vb = *(const bf8_t*)(hb + (row0 + r) * 128 + c * 8);
    int byte = (r * 512 + c * 16) ^ ((r & 7) << 4);
    *(bf8_t*)((char*)hs + byte) = vf;
    int byte2 = (r * 512 + 256 + c * 16) ^ ((r & 7) << 4);
    *(bf8_t*)((char*)hs + byte2) = vb;
  }
  __syncthreads();
  float acc[Kn];
  #pragma unroll
  for (int jj = 0; jj < Kn; jj++) acc[jj] = bd[jj];
  int r = tid;
  #pragma unroll 4
  for (int c = 0; c < 32; c++) {
    int byte = (r * 512 + c * 16) ^ ((r & 7) << 4);
    bf8_t v = *(const bf8_t*)((const char*)hs + byte);
    #pragma unroll
    for (int e = 0; e < 8; e++) {
      float h = (float)v[e];
      int k = c * 8 + e;
      #pragma unroll
      for (int jj = 0; jj < Kn; jj++)
        acc[jj] = fmaf(h, Wd[k * Kn + jj], acc[jj]);   // uniform -> scalar loads
    }
  }
  float m = acc[0];
  #pragma unroll
  for (int jj = 1; jj < Kn; jj++) m = fmaxf(m, acc[jj]);
  float s = 0.f;
  #pragma unroll
  for (int jj = 0; jj < Kn; jj++) { acc[jj] = __expf(acc[jj] - m); s += acc[jj]; }
  float inv = 1.f / s;
  int rg = (int)row0 + tid;          // h row index = t*Bn + b
  int b = rg & 255, t = rg >> 8;
  float* op = out + ((size_t)b * Tn + t) * Kn;
  #pragma unroll
  for (int jj = 0; jj < Kn; jj++) op[jj] = acc[jj] * inv;
}

// ---------- CRF log-likelihood: one wave per batch row ----------
__global__ __launch_bounds__(64) void k_crf(const float* __restrict__ logits,
                                            const int* __restrict__ labels,
                                            const int* __restrict__ lens_i,
                                            const float* __restrict__ trans,
                                            float* __restrict__ out_ll) {
  int b = blockIdx.x, lane = threadIdx.x;
  int len = lens_i[b];
  const float* lg = logits + (size_t)b * Tn * Kn;
  const int* lab = labels + (size_t)b * Tn;
  float sc = 0.f;
  for (int t = lane; t < Tn; t += 64) {
    if (t < len) {
      sc += lg[t * Kn + lab[t]];
      if (t >= 1) sc += trans[lab[t - 1] * Kn + lab[t]];
    }
  }
  for (int off = 32; off; off >>= 1) sc += __shfl_down(sc, off);
  bool act = lane < Kn;
  int jl = act ? lane : 0;
  float etr[Kn];
  #pragma unroll
  for (int i = 0; i < Kn; i++) etr[i] = __expf(trans[i * Kn + jl]);
  float a = act ? lg[jl] : -INFINITY;
  float lgv = (len > 1) ? lg[Kn + jl] : 0.f;
  for (int t = 1; t < len; t++) {
    float lgn = (t + 1 < len) ? lg[(t + 1) * Kn + jl] : 0.f;
    float m = a;
    for (int off = 8; off; off >>= 1) m = fmaxf(m, __shfl_xor(m, off, 16));
    float ea = __expf(a - m);
    float s = 0.f;
    #pragma unroll
    for (int i = 0; i < Kn; i++) s = fmaf(__shfl(ea, i), etr[i], s);
    float anew = m + __logf(s) + lgv;
    if (act) a = anew;
    lgv = lgn;
  }
  float m2 = a;
  for (int off = 8; off; off >>= 1) m2 = fmaxf(m2, __shfl_xor(m2, off, 16));
  float ea2 = act ? __expf(a - m2) : 0.f;
  float ssum = ea2;
  for (int off = 8; off; off >>= 1) ssum += __shfl_xor(ssum, off, 16);
  float logZ = m2 + __logf(ssum);
  if (lane == 0) out_ll[b] = sc - logZ;
}

extern "C" void kernel_launch(void* const* d_in, const int* in_sizes, int n_in,
                              void* d_out, int out_size, void* d_ws, size_t ws_size,
                              hipStream_t stream) {
  const int* text = (const int*)d_in[0];
  const int* labels = (const int*)d_in[1];
  const float* emb = (const float*)d_in[2];
  const float* Wf = (const float*)d_in[3];
  const float* Uf = (const float*)d_in[4];
  const float* bf_ = (const float*)d_in[5];
  const float* Wb = (const float*)d_in[6];
  const float* Ub = (const float*)d_in[7];
  const float* bb_ = (const float*)d_in[8];
  const float* Wd = (const float*)d_in[9];
  const float* bd = (const float*)d_in[10];
  const float* trans = (const float*)d_in[11];
  (void)in_sizes; (void)n_in; (void)out_size; (void)ws_size;

  float* out = (float*)d_out;
  float* out_logits = out;                       // [BT*K]
  float* out_lens = out + (size_t)BT * Kn;       // [B]
  float* out_ll = out_lens + Bn;                 // [B]

  char* ws = (char*)d_ws;
  size_t o = 0;
  int* lens_i = (int*)(ws + o);                o += 1024;
  unsigned short* wt = (unsigned short*)(ws + o);  o += (size_t)2 * G4 * 128 * 2;
  unsigned short* ut = (unsigned short*)(ws + o);  o += (size_t)2 * G4 * 128 * 2;
  unsigned short* xg = (unsigned short*)(ws + o);  o += (size_t)BT * 128 * 2;
  unsigned short* xw_s = (unsigned short*)(ws + o); o += (size_t)2 * BT * G4 * 2;  // [dir][t][b][512]
  unsigned short* hfb = (unsigned short*)(ws + o); o += (size_t)BT * Hn * 2;       // [t][b][128]
  unsigned short* hbb = (unsigned short*)(ws + o); o += (size_t)BT * Hn * 2;
  unsigned short* xwf = xw_s;
  unsigned short* xwb = xw_s + (size_t)BT * G4;

  hipLaunchKernelGGL(k_lens, dim3(Bn), dim3(64), 0, stream, text, lens_i, out_lens);
  hipLaunchKernelGGL(k_wt, dim3(1024), dim3(256), 0, stream, Wf, Wb, Uf, Ub, wt, ut);
  hipLaunchKernelGGL(k_gather, dim3(400), dim3(256), 0, stream, text, emb, xg);
  hipLaunchKernelGGL(k_gemm_xw, dim3(400, 8), dim3(256), 0, stream, xg, wt, bf_, bb_, xwf, xwb);
  hipLaunchKernelGGL(k_scan, dim3(32), dim3(512), 0, stream, ut, xw_s, hfb, hbb);
  hipLaunchKernelGGL(k_logits, dim3(400), dim3(128), 0, stream, hfb, hbb, Wd, bd, out_logits);
  hipLaunchKernelGGL(k_crf, dim3(Bn), dim3(64), 0, stream, out_logits, labels, lens_i, trans, out_ll);
}